// Round 9
// baseline (183.304 us; speedup 1.0000x reference)
//
#include <hip/hip_runtime.h>
#include <math.h>

typedef unsigned short u16;
typedef __attribute__((ext_vector_type(8))) short short8v;   // 8 bf16
typedef __attribute__((ext_vector_type(4))) float f32x4;

constexpr int B_  = 4;
constexpr int L_  = 8192;
constexpr int D_  = 128;
constexpr int N_  = 32;
constexpr int BL  = B_ * L_;          // 32768 rows
constexpr int CH  = 16;               // chunk rows (one gemm1 wave)
constexpr int NC  = L_ / CH;          // 512 chunks per batch
constexpr int SCH = 32;               // scan_main rows per block
constexpr int SNC = L_ / SCH;         // 256

// round-to-nearest-even f32 -> bf16
__device__ inline unsigned bfr(float x) {
    unsigned u = __float_as_uint(x);
    return (u + 0x7fffu + ((u >> 16) & 1u)) >> 16;
}
__device__ inline unsigned pkbf(float a, float b) { return bfr(a) | (bfr(b) << 16); }
__device__ inline float b2f(u16 h) { return __uint_as_float(((unsigned)h) << 16); }

// ---------------------------------------------------------------------------
// prep (single launch, grid (64, 8) x 512):
//  y=0 (bx<32): W_eff^T = (Wx[:, :128] @ Wdt)^T -> Wt0 rows 0..127 (bf16 [d][k])
//  y=1: W_x B/C cols^T -> Wt0 rows 128..191
//  y=2: W_f^T -> Wt2
//  y=3..5: conv taps^T -> Wtc
//  y=6: negAT[n][d] = -exp(A_log[d,n])*log2(e)
//  y=7: amax[d] = max_n negA
// ---------------------------------------------------------------------------
__global__ __launch_bounds__(512) void prep(
    const float* __restrict__ Wx, const float* __restrict__ Wdt,
    const float* __restrict__ Wf, const float* __restrict__ Wconv,
    const float* __restrict__ A_log,
    u16* __restrict__ Wt0, u16* __restrict__ Wt2, u16* __restrict__ Wtc,
    float* __restrict__ negAT, float* __restrict__ amax)
{
    const int y = blockIdx.y;
    const int tid = threadIdx.x;
    constexpr float L2E = 1.4426950408889634f;
    if (y == 0) {
        if (blockIdx.x >= 32) return;
        __shared__ float wd[128 * 128];
        #pragma unroll
        for (int j = 0; j < 8; ++j) {
            const int g = tid + j * 512;
            *reinterpret_cast<float4*>(&wd[g * 4]) =
                *reinterpret_cast<const float4*>(&Wdt[(size_t)g * 4]);
        }
        __syncthreads();
        const int k = blockIdx.x * 4 + (tid >> 7);
        const int d = tid & 127;
        float s = 0.f;
        #pragma unroll 8
        for (int j = 0; j < 128; ++j)
            s = fmaf(Wx[(size_t)k * 192 + j], wd[j * 128 + d], s);
        Wt0[d * 128 + k] = (u16)bfr(s);
        return;
    }
    const int t = blockIdx.x * 512 + tid;
    if (y == 1) {
        if (t >= 64 * 128) return;
        const int n = t >> 7, k = t & 127;
        Wt0[(128 + n) * 128 + k] = (u16)bfr(Wx[(size_t)k * 192 + 128 + n]);
    } else if (y == 2) {
        if (t >= 128 * 128) return;
        const int n = t >> 7, k = t & 127;
        Wt2[n * 128 + k] = (u16)bfr(Wf[(size_t)k * 128 + n]);
    } else if (y <= 5) {
        if (t >= 128 * 128) return;
        const int w = y - 3;
        const int n = t >> 7, k = t & 127;
        Wtc[((size_t)w * 128 + n) * 128 + k] = (u16)bfr(Wconv[((size_t)w * 128 + k) * 128 + n]);
    } else if (y == 6) {
        if (t >= 128 * 32) return;
        const int d = t >> 5, n = t & 31;
        negAT[n * 128 + d] = -expf(A_log[d * 32 + n]) * L2E;
    } else {
        if (t >= 128) return;
        float m = -1e30f;
        for (int n = 0; n < 32; ++n)
            m = fmaxf(m, -expf(A_log[t * 32 + n]) * L2E);
        amax[t] = m;
    }
}

// ---------------------------------------------------------------------------
// gemm1: x(BLx128) @ [W_eff | W_xB | W_xC](128x192), barrier-free main loop.
// BM=64, 256 threads (4 waves), grid 512 (>=2 blocks/CU for overlap).
// A-frags straight from global f32 (issued before the single barrier).
// Epilogue: softplus -> delta f32; chunk sums -> part[b][d][c]; bc = B*C.
// ---------------------------------------------------------------------------
__global__ __launch_bounds__(256) void gemm1(
    const float* __restrict__ x, const u16* __restrict__ Wt0,
    const float* __restrict__ b_dt,
    float* __restrict__ delta, float* __restrict__ bc,
    float* __restrict__ part)
{
    __shared__ __align__(16) u16 Blds[192 * 128];   // 48 KB, swizzled

    const int tid = threadIdx.x;
    const int r0 = blockIdx.x * 64;

    #pragma unroll
    for (int j = 0; j < 12; ++j) {   // 192 rows x 16 uint4 groups = 3072
        const int g = tid + j * 256;
        const int n = g >> 4, k8 = (g & 15) * 8;
        const uint4 p = *reinterpret_cast<const uint4*>(&Wt0[(size_t)n * 128 + k8]);
        *reinterpret_cast<uint4*>(&Blds[n * 128 + (k8 ^ ((n & 7) << 3))]) = p;
    }

    const int w = tid >> 6, lane = tid & 63;
    const int lr = lane & 15, kg = lane >> 4;
    const int arow = r0 + w * 16 + lr;

    float4 av[4][2];
    #pragma unroll
    for (int ks = 0; ks < 4; ++ks) {
        const float* src = &x[(size_t)arow * 128 + ks * 32 + kg * 8];
        av[ks][0] = *reinterpret_cast<const float4*>(src);
        av[ks][1] = *reinterpret_cast<const float4*>(src + 4);
    }
    __syncthreads();

    f32x4 acc[12] = {};
    #pragma unroll
    for (int ks = 0; ks < 4; ++ks) {
        uint4 ap;
        ap.x = pkbf(av[ks][0].x, av[ks][0].y);
        ap.y = pkbf(av[ks][0].z, av[ks][0].w);
        ap.z = pkbf(av[ks][1].x, av[ks][1].y);
        ap.w = pkbf(av[ks][1].z, av[ks][1].w);
        const short8v af = *reinterpret_cast<const short8v*>(&ap);
        const int kb = ks * 32 + kg * 8;
        #pragma unroll
        for (int nf = 0; nf < 12; ++nf) {
            const int n = nf * 16 + lr;
            const short8v bf = *reinterpret_cast<const short8v*>(
                &Blds[n * 128 + (kb ^ ((n & 7) << 3))]);
            acc[nf] = __builtin_amdgcn_mfma_f32_16x16x32_bf16(af, bf, acc[nf], 0, 0, 0);
        }
    }

    // ---- epilogue ----
    const int orow = r0 + w * 16;                  // wave's 16-row chunk base
    const int bb = orow >> 13;                     // batch
    const int chk = (orow & (L_ - 1)) >> 4;        // chunk index in batch
    #pragma unroll
    for (int nf = 0; nf < 8; ++nf) {
        const int col = nf * 16 + lr;
        const float bbv = b_dt[col];
        float v[4];
        #pragma unroll
        for (int q = 0; q < 4; ++q) {
            const float t = acc[nf][q] + bbv;
            v[q] = fmaxf(t, 0.f) + log1pf(expf(-fabsf(t)));   // stable softplus
        }
        const float g4 = v[0] + v[1] + v[2] + v[3];
        const float g0 = __shfl(g4, lr, 64);
        const float g1 = __shfl(g4, lr + 16, 64);
        const float g2 = __shfl(g4, lr + 32, 64);
        const float g3 = __shfl(g4, lr + 48, 64);
        const size_t rb = (size_t)(orow + kg * 4) * 128 + col;
        delta[rb + 0 * 128] = v[0];
        delta[rb + 1 * 128] = v[1];
        delta[rb + 2 * 128] = v[2];
        delta[rb + 3 * 128] = v[3];
        if (kg == 0)
            part[((size_t)bb * 128 + col) * NC + chk] = g0 + g1 + g2 + g3;
    }
    #pragma unroll
    for (int h2 = 0; h2 < 2; ++h2)
        #pragma unroll
        for (int q = 0; q < 4; ++q)
            bc[(size_t)(orow + kg * 4 + q) * 32 + h2 * 16 + lr] =
                acc[8 + h2][q] * acc[10 + h2][q];
}

// ---------------------------------------------------------------------------
// scan_main: per 32-row tile (grid (SNC, B) = 1024 blocks, 512 thr, 36KB LDS
// -> 4 blocks/CU):
//  P0: in-block exclusive chunk prefix: each thread-quad sums the raw
//      part[b][d][0..2cb) row from L2 (coalesced in c), shfl-reduce -> P_lds.
//  P1: stage delta tile (16KB) + negAT (16KB) + bc tile (4KB).
//  P2: serial 32-step walk reconstructs per-row S; h = dv*hv*(1+Dp)*
//      sum_n bc*exp2(S*negA) with underflow skip -> h_out f32 + hb bf16.
// ---------------------------------------------------------------------------
__global__ __launch_bounds__(512) void scan_main(
    const float* __restrict__ delta, const float* __restrict__ hprev,
    const float* __restrict__ bc, const float* __restrict__ negAT,
    const float* __restrict__ amax, const float* __restrict__ Dp,
    const float* __restrict__ part,
    float* __restrict__ h_out, u16* __restrict__ hb)
{
    __shared__ float delta_s[SCH * 128];          // 16 KB
    __shared__ float at_s[32 * 128];              // 16 KB  negAT[n][d]
    __shared__ float bc_s[SCH * 32];              // 4 KB
    __shared__ float P_lds[128 * 2];              // per-d (P0, P1)

    const int cb = blockIdx.x, b = blockIdx.y;
    const int tid = threadIdx.x;
    const size_t rowbase = (size_t)b * L_ + (size_t)cb * SCH;

    #pragma unroll
    for (int j = 0; j < 2; ++j) {     // delta tile: 1024 float4
        const int g = tid + j * 512;
        reinterpret_cast<float4*>(delta_s)[g] =
            reinterpret_cast<const float4*>(&delta[rowbase * 128])[g];
    }
    #pragma unroll
    for (int j = 0; j < 2; ++j) {     // negAT: 1024 float4
        const int g = tid + j * 512;
        reinterpret_cast<float4*>(at_s)[g] =
            reinterpret_cast<const float4*>(negAT)[g];
    }
    if (tid < 256)                    // 32x32 bc tile
        reinterpret_cast<float4*>(bc_s)[tid] =
            reinterpret_cast<const float4*>(&bc[rowbase * 32])[tid];

    // ---- P0: in-block exclusive prefix over chunks [0, 2cb) ----
    {
        const int dq = tid >> 2, j = tid & 3;
        const size_t pb = ((size_t)b * 128 + dq) * NC;
        const int Cend = cb * 2;
        float e0 = 0.f, e1 = 0.f;
        int c = j;
        for (; c + 4 < Cend; c += 8) {
            e0 += part[pb + c];
            e1 += part[pb + c + 4];
        }
        for (; c < Cend; c += 4) e0 += part[pb + c];
        float e = e0 + e1;
        e += __shfl_xor(e, 1, 64);
        e += __shfl_xor(e, 2, 64);
        if (j == 0) {
            const float extra = part[pb + Cend];
            P_lds[dq * 2]     = e;
            P_lds[dq * 2 + 1] = e + extra;
        }
    }

    const int d = tid & 127, r0 = tid >> 7;
    const float dp1 = 1.f + Dp[d];
    const float am = amax[d];
    __syncthreads();

    const float part0 = P_lds[d * 2];
    const float part1 = P_lds[d * 2 + 1];

    // reconstruct per-row exclusive S via serial walk (2 chunks of 16)
    float sv[8];
    {
        float s = part0;
        #pragma unroll
        for (int i = 0; i < 16; ++i) {
            if ((i & 3) == r0) sv[i >> 2] = s;
            s += delta_s[i * 128 + d];
        }
        s = part1;
        #pragma unroll
        for (int i = 16; i < 32; ++i) {
            if ((i & 3) == r0) sv[i >> 2] = s;
            s += delta_s[i * 128 + d];
        }
    }

    #pragma unroll 1
    for (int r = 0; r < 8; ++r) {
        const int row = r * 4 + r0;
        const size_t rb = (rowbase + row) * 128 + d;
        const float S = sv[r];
        float h = 0.f;
        if (__any(S * am >= -80.f)) {       // underflow skip
            const float dv = delta_s[row * 128 + d];
            const float hv = hprev[rb];
            float p0 = 0.f, p1 = 0.f, p2 = 0.f, p3 = 0.f;
            #pragma unroll
            for (int n4 = 0; n4 < 8; ++n4) {
                const float4 b4 = *reinterpret_cast<const float4*>(&bc_s[row * 32 + n4 * 4]);
                p0 = fmaf(b4.x, exp2f(S * at_s[(n4 * 4 + 0) * 128 + d]), p0);
                p1 = fmaf(b4.y, exp2f(S * at_s[(n4 * 4 + 1) * 128 + d]), p1);
                p2 = fmaf(b4.z, exp2f(S * at_s[(n4 * 4 + 2) * 128 + d]), p2);
                p3 = fmaf(b4.w, exp2f(S * at_s[(n4 * 4 + 3) * 128 + d]), p3);
            }
            h = dv * hv * ((p0 + p1) + (p2 + p3)) * dp1;
        }
        h_out[rb] = h;
        hb[rb] = (u16)bfr(h);
    }
}

// ---------------------------------------------------------------------------
// conv_fuse2: per 64-row tile (grid (L/64, B) = 512 blocks, 512 thr, 41KB
// LDS -> 2 blocks/CU):
//  P1: load hb rows r0-2 .. r0+77 -> hb_s (bf16, swizzled)
//  P2: ssm = relu(hb @ W_f + b_f) for 80 rows -> ssm_s (40 frag-units
//      balanced across 8 waves; W_f from L2); causal-zero rows < 0.
//  P3: conv3 MFMA (Wtc from L2) + relu + multiply by ssm -> fused.
// ---------------------------------------------------------------------------
__global__ __launch_bounds__(512) void conv_fuse2(
    const u16* __restrict__ hb, const u16* __restrict__ Wt2,
    const float* __restrict__ b_f, const u16* __restrict__ Wtc,
    const float* __restrict__ cbias, float* __restrict__ fused)
{
    __shared__ __align__(16) u16 hb_s[80 * 128];    // 20.5 KB swizzled
    __shared__ __align__(16) u16 ssm_s[80 * 128];   // 20.5 KB swizzled

    const int tid = threadIdx.x;
    const int bb = blockIdx.y;
    const int r0 = blockIdx.x * 64;
    const u16* hbB = hb + (size_t)bb * L_ * 128;

    #pragma unroll
    for (int j = 0; j < 3; ++j) {   // 80 rows x 16 uint4 groups = 1280
        const int g = tid + j * 512;
        if (g < 80 * 16) {
            const int s = g >> 4, k8 = (g & 15) * 8;
            const int gr = r0 - 2 + s;
            uint4 p = make_uint4(0, 0, 0, 0);
            if (gr >= 0 && gr < L_)
                p = *reinterpret_cast<const uint4*>(&hbB[(size_t)gr * 128 + k8]);
            *reinterpret_cast<uint4*>(&hb_s[s * 128 + (k8 ^ ((s & 7) << 3))]) = p;
        }
    }
    __syncthreads();

    const int w = tid >> 6, lane = tid & 63;
    const int lr = lane & 15, kg = lane >> 4;

    // P2: 40 (sm, nf) frag-units over 8 waves (5 each)
    #pragma unroll
    for (int ui = 0; ui < 5; ++ui) {
        const int u = w * 5 + ui;
        const int sm = u >> 3, nf = u & 7;
        const int col = nf * 16 + lr;
        f32x4 a = {};
        #pragma unroll
        for (int ks = 0; ks < 4; ++ks) {
            const int kb = ks * 32 + kg * 8;
            const int sr = sm * 16 + lr;
            const short8v af = *reinterpret_cast<const short8v*>(
                &hb_s[sr * 128 + (kb ^ ((sr & 7) << 3))]);
            const short8v bf = *reinterpret_cast<const short8v*>(
                &Wt2[(size_t)col * 128 + kb]);
            a = __builtin_amdgcn_mfma_f32_16x16x32_bf16(af, bf, a, 0, 0, 0);
        }
        const float bbv = b_f[col];
        #pragma unroll
        for (int q = 0; q < 4; ++q) {
            const int s2 = sm * 16 + kg * 4 + q;
            float vv = fmaxf(a[q] + bbv, 0.f);
            if (r0 - 2 + s2 < 0) vv = 0.f;          // causal left pad
            ssm_s[s2 * 128 + (col ^ ((s2 & 7) << 3))] = (u16)bfr(vv);
        }
    }
    __syncthreads();

    // P3: conv3 + fused multiply
    const int wm = w >> 2, wn = w & 3;
    f32x4 acc[2][2] = {};
    #pragma unroll
    for (int ks = 0; ks < 4; ++ks) {
        const int k8 = ks * 32 + kg * 8;
        short8v af[2][3];
        #pragma unroll
        for (int m = 0; m < 2; ++m)
            #pragma unroll
            for (int t = 0; t < 3; ++t) {
                const int ri = wm * 32 + m * 16 + lr + t;
                af[m][t] = *reinterpret_cast<const short8v*>(
                    &ssm_s[ri * 128 + (k8 ^ ((ri & 7) << 3))]);
            }
        #pragma unroll
        for (int nf = 0; nf < 2; ++nf) {
            const int col = wn * 32 + nf * 16 + lr;
            #pragma unroll
            for (int t = 0; t < 3; ++t) {
                const short8v bfg = *reinterpret_cast<const short8v*>(
                    &Wtc[((size_t)t * 128 + col) * 128 + k8]);
                acc[0][nf] = __builtin_amdgcn_mfma_f32_16x16x32_bf16(af[0][t], bfg, acc[0][nf], 0, 0, 0);
                acc[1][nf] = __builtin_amdgcn_mfma_f32_16x16x32_bf16(af[1][t], bfg, acc[1][nf], 0, 0, 0);
            }
        }
    }
    #pragma unroll
    for (int nf = 0; nf < 2; ++nf) {
        const int col = wn * 32 + nf * 16 + lr;
        const float cb2 = cbias[col];
        #pragma unroll
        for (int m = 0; m < 2; ++m)
            #pragma unroll
            for (int q = 0; q < 4; ++q) {
                const int ro = wm * 32 + m * 16 + kg * 4 + q;
                const int ri = ro + 2;
                const u16 sh = ssm_s[ri * 128 + (col ^ ((ri & 7) << 3))];
                const float cv = fmaxf(acc[m][nf][q] + cb2, 0.f);
                fused[((size_t)bb * L_ + r0 + ro) * 128 + col] = b2f(sh) * cv;
            }
    }
}

// ---------------------------------------------------------------------------
extern "C" void kernel_launch(void* const* d_in, const int* in_sizes, int n_in,
                              void* d_out, int out_size, void* d_ws, size_t ws_size,
                              hipStream_t stream)
{
    const float* x      = (const float*)d_in[0];
    const float* hprev  = (const float*)d_in[1];
    const float* A_log  = (const float*)d_in[2];
    const float* Dp     = (const float*)d_in[3];
    const float* W_x    = (const float*)d_in[4];
    const float* W_dt   = (const float*)d_in[5];
    const float* b_dt   = (const float*)d_in[6];
    const float* conv_w = (const float*)d_in[7];
    const float* conv_b = (const float*)d_in[8];
    const float* W_f    = (const float*)d_in[9];
    const float* b_f    = (const float*)d_in[10];

    float* out   = (float*)d_out;                       // fused_output
    float* h_out = out + (size_t)BL * D_;               // h_t

    char* ws = (char*)d_ws;
    float* delta = (float*)ws;                  ws += (size_t)BL * 128 * 4;
    float* bcb   = (float*)ws;                  ws += (size_t)BL * 32 * 4;
    float* part  = (float*)ws;                  ws += (size_t)B_ * 128 * NC * 4;
    float* negAT = (float*)ws;                  ws += (size_t)N_ * 128 * 4;
    float* amaxb = (float*)ws;                  ws += (size_t)128 * 4;
    u16*   Wt0   = (u16*)ws;                    ws += (size_t)192 * 128 * 2;
    u16*   Wt2   = (u16*)ws;                    ws += (size_t)128 * 128 * 2;
    u16*   Wtc   = (u16*)ws;                    ws += (size_t)3 * 128 * 128 * 2;
    u16*   hb    = (u16*)ws;

    prep<<<dim3(64, 8), dim3(512), 0, stream>>>(
        W_x, W_dt, W_f, conv_w, A_log, Wt0, Wt2, Wtc, negAT, amaxb);
    gemm1<<<dim3(BL / 64), dim3(256), 0, stream>>>(
        x, Wt0, b_dt, delta, bcb, part);
    scan_main<<<dim3(SNC, B_), dim3(512), 0, stream>>>(
        delta, hprev, bcb, negAT, amaxb, Dp, part, h_out, hb);
    conv_fuse2<<<dim3(L_ / 64, B_), dim3(512), 0, stream>>>(
        hb, Wt2, b_f, Wtc, conv_b, out);
}

// Round 10
// 174.442 us; speedup vs baseline: 1.0508x; 1.0508x over previous
//
#include <hip/hip_runtime.h>
#include <math.h>

typedef unsigned short u16;
typedef __attribute__((ext_vector_type(8))) short short8v;   // 8 bf16
typedef __attribute__((ext_vector_type(4))) float f32x4;

constexpr int B_  = 4;
constexpr int L_  = 8192;
constexpr int D_  = 128;
constexpr int N_  = 32;
constexpr int BL  = B_ * L_;          // 32768 rows
constexpr int CH  = 16;               // chunk rows (one gemm1 wave)
constexpr int NC  = L_ / CH;          // 512 chunks per batch
constexpr int SCH = 32;               // scan_main rows per block
constexpr int SNC = L_ / SCH;         // 256

// round-to-nearest-even f32 -> bf16
__device__ inline unsigned bfr(float x) {
    unsigned u = __float_as_uint(x);
    return (u + 0x7fffu + ((u >> 16) & 1u)) >> 16;
}
__device__ inline unsigned pkbf(float a, float b) { return bfr(a) | (bfr(b) << 16); }
__device__ inline float b2f(u16 h) { return __uint_as_float(((unsigned)h) << 16); }

// ---------------------------------------------------------------------------
// prep (single launch, grid (64, 8) x 512):
//  y=0 (bx<32): W_eff^T = (Wx[:, :128] @ Wdt)^T -> Wt0 rows 0..127 (bf16 [d][k])
//  y=1: W_x B/C cols^T -> Wt0 rows 128..191
//  y=2: W_f^T -> Wt2
//  y=3..5: conv taps^T -> Wtc
//  y=6: negAT[n][d] = -exp(A_log[d,n])*log2(e)
//  y=7: amax[d] = max_n negA
// ---------------------------------------------------------------------------
__global__ __launch_bounds__(512) void prep(
    const float* __restrict__ Wx, const float* __restrict__ Wdt,
    const float* __restrict__ Wf, const float* __restrict__ Wconv,
    const float* __restrict__ A_log,
    u16* __restrict__ Wt0, u16* __restrict__ Wt2, u16* __restrict__ Wtc,
    float* __restrict__ negAT, float* __restrict__ amax)
{
    const int y = blockIdx.y;
    const int tid = threadIdx.x;
    constexpr float L2E = 1.4426950408889634f;
    if (y == 0) {
        if (blockIdx.x >= 32) return;
        __shared__ float wd[128 * 128];
        #pragma unroll
        for (int j = 0; j < 8; ++j) {
            const int g = tid + j * 512;
            *reinterpret_cast<float4*>(&wd[g * 4]) =
                *reinterpret_cast<const float4*>(&Wdt[(size_t)g * 4]);
        }
        __syncthreads();
        const int k = blockIdx.x * 4 + (tid >> 7);
        const int d = tid & 127;
        float s = 0.f;
        #pragma unroll 8
        for (int j = 0; j < 128; ++j)
            s = fmaf(Wx[(size_t)k * 192 + j], wd[j * 128 + d], s);
        Wt0[d * 128 + k] = (u16)bfr(s);
        return;
    }
    const int t = blockIdx.x * 512 + tid;
    if (y == 1) {
        if (t >= 64 * 128) return;
        const int n = t >> 7, k = t & 127;
        Wt0[(128 + n) * 128 + k] = (u16)bfr(Wx[(size_t)k * 192 + 128 + n]);
    } else if (y == 2) {
        if (t >= 128 * 128) return;
        const int n = t >> 7, k = t & 127;
        Wt2[n * 128 + k] = (u16)bfr(Wf[(size_t)k * 128 + n]);
    } else if (y <= 5) {
        if (t >= 128 * 128) return;
        const int w = y - 3;
        const int n = t >> 7, k = t & 127;
        Wtc[((size_t)w * 128 + n) * 128 + k] = (u16)bfr(Wconv[((size_t)w * 128 + k) * 128 + n]);
    } else if (y == 6) {
        if (t >= 128 * 32) return;
        const int d = t >> 5, n = t & 31;
        negAT[n * 128 + d] = -expf(A_log[d * 32 + n]) * L2E;
    } else {
        if (t >= 128) return;
        float m = -1e30f;
        for (int n = 0; n < 32; ++n)
            m = fmaxf(m, -expf(A_log[t * 32 + n]) * L2E);
        amax[t] = m;
    }
}

// ---------------------------------------------------------------------------
// gemm1: x(BLx128) @ [W_eff | W_xB | W_xC](128x192), barrier-free main loop.
// BM=64, 256 threads (4 waves), grid 512. A-frags straight from global f32.
// Epilogue: softplus -> delta f32; chunk sums -> part[b][d][c]; bc = B*C.
// ---------------------------------------------------------------------------
__global__ __launch_bounds__(256) void gemm1(
    const float* __restrict__ x, const u16* __restrict__ Wt0,
    const float* __restrict__ b_dt,
    float* __restrict__ delta, float* __restrict__ bc,
    float* __restrict__ part)
{
    __shared__ __align__(16) u16 Blds[192 * 128];   // 48 KB, swizzled

    const int tid = threadIdx.x;
    const int r0 = blockIdx.x * 64;

    #pragma unroll
    for (int j = 0; j < 12; ++j) {   // 192 rows x 16 uint4 groups = 3072
        const int g = tid + j * 256;
        const int n = g >> 4, k8 = (g & 15) * 8;
        const uint4 p = *reinterpret_cast<const uint4*>(&Wt0[(size_t)n * 128 + k8]);
        *reinterpret_cast<uint4*>(&Blds[n * 128 + (k8 ^ ((n & 7) << 3))]) = p;
    }

    const int w = tid >> 6, lane = tid & 63;
    const int lr = lane & 15, kg = lane >> 4;
    const int arow = r0 + w * 16 + lr;

    float4 av[4][2];
    #pragma unroll
    for (int ks = 0; ks < 4; ++ks) {
        const float* src = &x[(size_t)arow * 128 + ks * 32 + kg * 8];
        av[ks][0] = *reinterpret_cast<const float4*>(src);
        av[ks][1] = *reinterpret_cast<const float4*>(src + 4);
    }
    __syncthreads();

    f32x4 acc[12] = {};
    #pragma unroll
    for (int ks = 0; ks < 4; ++ks) {
        uint4 ap;
        ap.x = pkbf(av[ks][0].x, av[ks][0].y);
        ap.y = pkbf(av[ks][0].z, av[ks][0].w);
        ap.z = pkbf(av[ks][1].x, av[ks][1].y);
        ap.w = pkbf(av[ks][1].z, av[ks][1].w);
        const short8v af = *reinterpret_cast<const short8v*>(&ap);
        const int kb = ks * 32 + kg * 8;
        #pragma unroll
        for (int nf = 0; nf < 12; ++nf) {
            const int n = nf * 16 + lr;
            const short8v bf = *reinterpret_cast<const short8v*>(
                &Blds[n * 128 + (kb ^ ((n & 7) << 3))]);
            acc[nf] = __builtin_amdgcn_mfma_f32_16x16x32_bf16(af, bf, acc[nf], 0, 0, 0);
        }
    }

    // ---- epilogue ----
    const int orow = r0 + w * 16;                  // wave's 16-row chunk base
    const int bb = orow >> 13;                     // batch
    const int chk = (orow & (L_ - 1)) >> 4;        // chunk index in batch
    #pragma unroll
    for (int nf = 0; nf < 8; ++nf) {
        const int col = nf * 16 + lr;
        const float bbv = b_dt[col];
        float v[4];
        #pragma unroll
        for (int q = 0; q < 4; ++q) {
            const float t = acc[nf][q] + bbv;
            v[q] = fmaxf(t, 0.f) + log1pf(expf(-fabsf(t)));   // stable softplus
        }
        const float g4 = v[0] + v[1] + v[2] + v[3];
        const float g0 = __shfl(g4, lr, 64);
        const float g1 = __shfl(g4, lr + 16, 64);
        const float g2 = __shfl(g4, lr + 32, 64);
        const float g3 = __shfl(g4, lr + 48, 64);
        const size_t rb = (size_t)(orow + kg * 4) * 128 + col;
        delta[rb + 0 * 128] = v[0];
        delta[rb + 1 * 128] = v[1];
        delta[rb + 2 * 128] = v[2];
        delta[rb + 3 * 128] = v[3];
        if (kg == 0)
            part[((size_t)bb * 128 + col) * NC + chk] = g0 + g1 + g2 + g3;
    }
    #pragma unroll
    for (int h2 = 0; h2 < 2; ++h2)
        #pragma unroll
        for (int q = 0; q < 4; ++q)
            bc[(size_t)(orow + kg * 4 + q) * 32 + h2 * 16 + lr] =
                acc[8 + h2][q] * acc[10 + h2][q];
}

// ---------------------------------------------------------------------------
// scan_prefix: exclusive prefix over NC=512 chunks per (b,d); reads the raw
// sums COALESCED from part[b][d][c], writes exclusive prefix TRANSPOSED to
// part2[b][c][d] (so scan_main's per-d reads are coalesced). grid (B, D).
// ---------------------------------------------------------------------------
__global__ __launch_bounds__(512) void scan_prefix(
    const float* __restrict__ part, float* __restrict__ part2)
{
    const int b = blockIdx.x, d = blockIdx.y;
    const int c = threadIdx.x, w = c >> 6, lane = c & 63;
    const size_t base = ((size_t)b * 128 + d) * NC;
    const float v = part[base + c];
    float s = v;
    #pragma unroll
    for (int off = 1; off < 64; off <<= 1) {
        const float t = __shfl_up(s, off, 64);
        if (lane >= off) s += t;
    }
    __shared__ float wsum[8];
    if (lane == 63) wsum[w] = s;
    __syncthreads();
    float add = 0.f;
    #pragma unroll
    for (int i = 0; i < 8; ++i)
        if (i < w) add += wsum[i];
    part2[((size_t)b * NC + c) * 128 + d] = s + add - v;   // exclusive
}

// ---------------------------------------------------------------------------
// scan_main: per 32-row tile (grid (SNC, B) = 1024 blocks, 512 thr):
//  flag: S_min = part2[b][2cb][d]; if S_min*amax < -80 for ALL d, every
//        exp2 underflows -> whole tile is exactly 0: coalesced zero-stores,
//        no staging, no hprev reads (~2/3 of blocks).
//  else: stage delta/negAT/bc, serial 32-walk for per-row S, per-row
//        __any skip, h = dv*hv*(1+Dp)*sum_n bc*exp2(S*negA).
// ---------------------------------------------------------------------------
__global__ __launch_bounds__(512, 4) void scan_main(
    const float* __restrict__ delta, const float* __restrict__ hprev,
    const float* __restrict__ bc, const float* __restrict__ negAT,
    const float* __restrict__ amax, const float* __restrict__ Dp,
    const float* __restrict__ part2,
    float* __restrict__ h_out, u16* __restrict__ hb)
{
    __shared__ float delta_s[SCH * 128];          // 16 KB
    __shared__ float at_s[32 * 128];              // 16 KB  negAT[n][d]
    __shared__ float bc_s[SCH * 32];              // 4 KB
    __shared__ int   wflag[8];

    const int cb = blockIdx.x, b = blockIdx.y;
    const int tid = threadIdx.x;
    const size_t rowbase = (size_t)b * L_ + (size_t)cb * SCH;
    const int d = tid & 127, r0 = tid >> 7;

    const float am = amax[d];
    const size_t p2b = ((size_t)b * NC + (size_t)cb * 2) * 128 + d;
    const float part0 = part2[p2b];
    const float part1 = part2[p2b + 128];

    const bool need = (part0 * am >= -80.f);
    const unsigned long long mask = __ballot(need);
    if ((tid & 63) == 0) wflag[tid >> 6] = (mask != 0ull);
    __syncthreads();
    const int anyneed = wflag[0] | wflag[1] | wflag[2] | wflag[3] |
                        wflag[4] | wflag[5] | wflag[6] | wflag[7];

    if (!anyneed) {
        // ---- fast path: whole 32x128 tile underflows to exactly 0 ----
        float4 z4 = make_float4(0.f, 0.f, 0.f, 0.f);
        float4* ho = reinterpret_cast<float4*>(&h_out[rowbase * 128]);
        #pragma unroll
        for (int j = 0; j < 2; ++j)
            ho[tid + j * 512] = z4;
        uint4 zi = make_uint4(0, 0, 0, 0);
        reinterpret_cast<uint4*>(&hb[rowbase * 128])[tid] = zi;
        return;
    }

    // ---- slow path ----
    #pragma unroll
    for (int j = 0; j < 2; ++j) {     // delta tile: 1024 float4
        const int g = tid + j * 512;
        reinterpret_cast<float4*>(delta_s)[g] =
            reinterpret_cast<const float4*>(&delta[rowbase * 128])[g];
    }
    #pragma unroll
    for (int j = 0; j < 2; ++j) {     // negAT: 1024 float4
        const int g = tid + j * 512;
        reinterpret_cast<float4*>(at_s)[g] =
            reinterpret_cast<const float4*>(negAT)[g];
    }
    if (tid < 256)                    // 32x32 bc tile
        reinterpret_cast<float4*>(bc_s)[tid] =
            reinterpret_cast<const float4*>(&bc[rowbase * 32])[tid];

    const float dp1 = 1.f + Dp[d];
    __syncthreads();

    // reconstruct per-row exclusive S via serial walk (2 chunks of 16)
    float sv[8];
    {
        float s = part0;
        #pragma unroll
        for (int i = 0; i < 16; ++i) {
            if ((i & 3) == r0) sv[i >> 2] = s;
            s += delta_s[i * 128 + d];
        }
        s = part1;
        #pragma unroll
        for (int i = 16; i < 32; ++i) {
            if ((i & 3) == r0) sv[i >> 2] = s;
            s += delta_s[i * 128 + d];
        }
    }

    #pragma unroll 1
    for (int r = 0; r < 8; ++r) {
        const int row = r * 4 + r0;
        const size_t rb = (rowbase + row) * 128 + d;
        const float S = sv[r];
        float h = 0.f;
        if (__any(S * am >= -80.f)) {       // per-row underflow skip
            const float dv = delta_s[row * 128 + d];
            const float hv = hprev[rb];
            float p0 = 0.f, p1 = 0.f, p2 = 0.f, p3 = 0.f;
            #pragma unroll
            for (int n4 = 0; n4 < 8; ++n4) {
                const float4 b4 = *reinterpret_cast<const float4*>(&bc_s[row * 32 + n4 * 4]);
                p0 = fmaf(b4.x, exp2f(S * at_s[(n4 * 4 + 0) * 128 + d]), p0);
                p1 = fmaf(b4.y, exp2f(S * at_s[(n4 * 4 + 1) * 128 + d]), p1);
                p2 = fmaf(b4.z, exp2f(S * at_s[(n4 * 4 + 2) * 128 + d]), p2);
                p3 = fmaf(b4.w, exp2f(S * at_s[(n4 * 4 + 3) * 128 + d]), p3);
            }
            h = dv * hv * ((p0 + p1) + (p2 + p3)) * dp1;
        }
        h_out[rb] = h;
        hb[rb] = (u16)bfr(h);
    }
}

// ---------------------------------------------------------------------------
// conv_fuse2: per 64-row tile (grid (L/64, B) = 512 blocks, 512 thr):
//  P1: load hb rows r0-2 .. r0+77 -> hb_s (bf16, swizzled)
//  P2: ssm = relu(hb @ W_f + b_f) for 80 rows -> ssm_s (W_f from L2)
//  P3: conv3 MFMA (Wtc from L2) + relu + multiply by ssm -> fused.
// ---------------------------------------------------------------------------
__global__ __launch_bounds__(512) void conv_fuse2(
    const u16* __restrict__ hb, const u16* __restrict__ Wt2,
    const float* __restrict__ b_f, const u16* __restrict__ Wtc,
    const float* __restrict__ cbias, float* __restrict__ fused)
{
    __shared__ __align__(16) u16 hb_s[80 * 128];    // 20.5 KB swizzled
    __shared__ __align__(16) u16 ssm_s[80 * 128];   // 20.5 KB swizzled

    const int tid = threadIdx.x;
    const int bb = blockIdx.y;
    const int r0 = blockIdx.x * 64;
    const u16* hbB = hb + (size_t)bb * L_ * 128;

    #pragma unroll
    for (int j = 0; j < 3; ++j) {   // 80 rows x 16 uint4 groups = 1280
        const int g = tid + j * 512;
        if (g < 80 * 16) {
            const int s = g >> 4, k8 = (g & 15) * 8;
            const int gr = r0 - 2 + s;
            uint4 p = make_uint4(0, 0, 0, 0);
            if (gr >= 0 && gr < L_)
                p = *reinterpret_cast<const uint4*>(&hbB[(size_t)gr * 128 + k8]);
            *reinterpret_cast<uint4*>(&hb_s[s * 128 + (k8 ^ ((s & 7) << 3))]) = p;
        }
    }
    __syncthreads();

    const int w = tid >> 6, lane = tid & 63;
    const int lr = lane & 15, kg = lane >> 4;

    // P2: 40 (sm, nf) frag-units over 8 waves (5 each)
    #pragma unroll
    for (int ui = 0; ui < 5; ++ui) {
        const int u = w * 5 + ui;
        const int sm = u >> 3, nf = u & 7;
        const int col = nf * 16 + lr;
        f32x4 a = {};
        #pragma unroll
        for (int ks = 0; ks < 4; ++ks) {
            const int kb = ks * 32 + kg * 8;
            const int sr = sm * 16 + lr;
            const short8v af = *reinterpret_cast<const short8v*>(
                &hb_s[sr * 128 + (kb ^ ((sr & 7) << 3))]);
            const short8v bf = *reinterpret_cast<const short8v*>(
                &Wt2[(size_t)col * 128 + kb]);
            a = __builtin_amdgcn_mfma_f32_16x16x32_bf16(af, bf, a, 0, 0, 0);
        }
        const float bbv = b_f[col];
        #pragma unroll
        for (int q = 0; q < 4; ++q) {
            const int s2 = sm * 16 + kg * 4 + q;
            float vv = fmaxf(a[q] + bbv, 0.f);
            if (r0 - 2 + s2 < 0) vv = 0.f;          // causal left pad
            ssm_s[s2 * 128 + (col ^ ((s2 & 7) << 3))] = (u16)bfr(vv);
        }
    }
    __syncthreads();

    // P3: conv3 + fused multiply
    const int wm = w >> 2, wn = w & 3;
    f32x4 acc[2][2] = {};
    #pragma unroll
    for (int ks = 0; ks < 4; ++ks) {
        const int k8 = ks * 32 + kg * 8;
        short8v af[2][3];
        #pragma unroll
        for (int m = 0; m < 2; ++m)
            #pragma unroll
            for (int t = 0; t < 3; ++t) {
                const int ri = wm * 32 + m * 16 + lr + t;
                af[m][t] = *reinterpret_cast<const short8v*>(
                    &ssm_s[ri * 128 + (k8 ^ ((ri & 7) << 3))]);
            }
        #pragma unroll
        for (int nf = 0; nf < 2; ++nf) {
            const int col = wn * 32 + nf * 16 + lr;
            #pragma unroll
            for (int t = 0; t < 3; ++t) {
                const short8v bfg = *reinterpret_cast<const short8v*>(
                    &Wtc[((size_t)t * 128 + col) * 128 + k8]);
                acc[0][nf] = __builtin_amdgcn_mfma_f32_16x16x32_bf16(af[0][t], bfg, acc[0][nf], 0, 0, 0);
                acc[1][nf] = __builtin_amdgcn_mfma_f32_16x16x32_bf16(af[1][t], bfg, acc[1][nf], 0, 0, 0);
            }
        }
    }
    #pragma unroll
    for (int nf = 0; nf < 2; ++nf) {
        const int col = wn * 32 + nf * 16 + lr;
        const float cb2 = cbias[col];
        #pragma unroll
        for (int m = 0; m < 2; ++m)
            #pragma unroll
            for (int q = 0; q < 4; ++q) {
                const int ro = wm * 32 + m * 16 + kg * 4 + q;
                const int ri = ro + 2;
                const u16 sh = ssm_s[ri * 128 + (col ^ ((ri & 7) << 3))];
                const float cv = fmaxf(acc[m][nf][q] + cb2, 0.f);
                fused[((size_t)bb * L_ + r0 + ro) * 128 + col] = b2f(sh) * cv;
            }
    }
}

// ---------------------------------------------------------------------------
extern "C" void kernel_launch(void* const* d_in, const int* in_sizes, int n_in,
                              void* d_out, int out_size, void* d_ws, size_t ws_size,
                              hipStream_t stream)
{
    const float* x      = (const float*)d_in[0];
    const float* hprev  = (const float*)d_in[1];
    const float* A_log  = (const float*)d_in[2];
    const float* Dp     = (const float*)d_in[3];
    const float* W_x    = (const float*)d_in[4];
    const float* W_dt   = (const float*)d_in[5];
    const float* b_dt   = (const float*)d_in[6];
    const float* conv_w = (const float*)d_in[7];
    const float* conv_b = (const float*)d_in[8];
    const float* W_f    = (const float*)d_in[9];
    const float* b_f    = (const float*)d_in[10];

    float* out   = (float*)d_out;                       // fused_output
    float* h_out = out + (size_t)BL * D_;               // h_t

    char* ws = (char*)d_ws;
    float* delta = (float*)ws;                  ws += (size_t)BL * 128 * 4;
    float* bcb   = (float*)ws;                  ws += (size_t)BL * 32 * 4;
    float* part  = (float*)ws;                  ws += (size_t)B_ * 128 * NC * 4;
    float* part2 = (float*)ws;                  ws += (size_t)B_ * NC * 128 * 4;
    float* negAT = (float*)ws;                  ws += (size_t)N_ * 128 * 4;
    float* amaxb = (float*)ws;                  ws += (size_t)128 * 4;
    u16*   Wt0   = (u16*)ws;                    ws += (size_t)192 * 128 * 2;
    u16*   Wt2   = (u16*)ws;                    ws += (size_t)128 * 128 * 2;
    u16*   Wtc   = (u16*)ws;                    ws += (size_t)3 * 128 * 128 * 2;
    u16*   hb    = (u16*)ws;

    prep<<<dim3(64, 8), dim3(512), 0, stream>>>(
        W_x, W_dt, W_f, conv_w, A_log, Wt0, Wt2, Wtc, negAT, amaxb);
    gemm1<<<dim3(BL / 64), dim3(256), 0, stream>>>(
        x, Wt0, b_dt, delta, bcb, part);
    scan_prefix<<<dim3(B_, D_), dim3(512), 0, stream>>>(part, part2);
    scan_main<<<dim3(SNC, B_), dim3(512), 0, stream>>>(
        delta, hprev, bcb, negAT, amaxb, Dp, part2, h_out, hb);
    conv_fuse2<<<dim3(L_ / 64, B_), dim3(512), 0, stream>>>(
        hb, Wt2, b_f, Wtc, conv_b, out);
}